// Round 11
// baseline (115.173 us; speedup 1.0000x reference)
//
#include <hip/hip_runtime.h>
#include <math.h>

#define BB 32
#define NN 8400
#define MM 32
#define NC 80
#define PD 85
#define TOPK 10
#define FLT_BIG 3.4e38f

__device__ __forceinline__ float bcef_(float x, float t) {
    return fmaxf(x, 0.0f) - x * t + log1pf(expf(-fabsf(x)));
}

// fast hardware-native helpers: v_exp/v_log/v_rcp/v_sqrt, ~1-2 ulp
__device__ __forceinline__ float frcp_(float x)  { return __builtin_amdgcn_rcpf(x); }
__device__ __forceinline__ float fsqrt_(float x) { return __builtin_amdgcn_sqrtf(x); }
__device__ __forceinline__ float fsig_(float x)  { return frcp_(1.0f + __expf(-x)); }

// shared by kC and kD so matched-gt argmin sees bit-consistent costs
__device__ __forceinline__ float iou_(float4 pb, float gx1, float gy1,
                                      float gx2, float gy2, float ga) {
    float ix1 = fmaxf(gx1, pb.x), iy1 = fmaxf(gy1, pb.y);
    float ix2 = fminf(gx2, pb.z), iy2 = fminf(gy2, pb.w);
    float inter = fmaxf(ix2 - ix1, 0.0f) * fmaxf(iy2 - iy1, 0.0f);
    float pa = fmaxf(pb.z - pb.x, 0.0f) * fmaxf(pb.w - pb.y, 0.0f);
    float uni = ga + pa - inter + 1e-7f;
    return inter * frcp_(uni);
}
__device__ __forceinline__ float cost_(float cl, float so_n, float base_n, float iou) {
    float s = fsqrt_(fsig_(cl) * so_n);
    float lp = __logf(s + 1e-7f);
    float lq = __logf(1.0f - s + 1e-7f);
    return base_n - lp + lq - 3.0f * __logf(iou + 1e-8f);
}

// ---- Kernel A: per-row precompute (no cost matrix) ------------------------
// Wave-per-2-rows skeleton from the proven kAB. Per-row outputs always;
// class-sum `base` only for rows with >=1 in-box GT (per-row ballot guards).
// Fully-skipped pairs never load their pred rows.
__global__ void __launch_bounds__(256) kA(const float* __restrict__ pred,
                                          const float* __restrict__ tgt,
                                          float4* __restrict__ pxyxy,
                                          float2* __restrict__ cxy,
                                          float* __restrict__ base,
                                          float* __restrict__ so,
                                          float* __restrict__ objlogit,
                                          unsigned int* __restrict__ mask) {
    const int tid = threadIdx.x;
    const int lane = tid & 63, wid = tid >> 6;
    const int rs = lane >> 5, g = lane & 31;
    const int b = blockIdx.y;
    const int tile = blockIdx.x;             // 525 tiles of 16 rows

    // per-lane GT box (for in-box test)
    const float* t = tgt + ((size_t)b * MM + g) * 5;
    const float gx1 = t[1] - t[3] * 0.5f, gy1 = t[2] - t[4] * 0.5f;
    const float gx2 = t[1] + t[3] * 0.5f, gy2 = t[2] + t[4] * 0.5f;

    for (int itr = 0; itr < 2; ++itr) {
        const int pl = wid * 2 + itr;        // pair-local 0..7
        const int r0 = tile * 16 + pl * 2;   // global row (even)
        const size_t off = ((size_t)b * NN + r0) * PD;

        const float cxs = pred[off + rs * PD];
        const float cys = pred[off + rs * PD + 1];
        const bool inb = (cxs > gx1) && (cxs < gx2) && (cys > gy1) && (cys < gy2);
        const unsigned long long bal = __ballot(inb);
        const bool r0a = (bal & 0xFFFFFFFFull) != 0ull;   // lanes 0-31 = row0
        const bool r1a = (bal >> 32) != 0ull;             // lanes 32-63 = row1

        if (lane < 2) {                      // per-row small outputs
            const float* pr = pred + off + lane * PD;
            float cx = pr[0], cy = pr[1], w = pr[2], h = pr[3], ol = pr[4];
            size_t gi = (size_t)b * NN + r0 + lane;
            pxyxy[gi] = make_float4(cx - w * 0.5f, cy - h * 0.5f,
                                    cx + w * 0.5f, cy + h * 0.5f);
            cxy[gi] = make_float2(cx, cy);
            objlogit[gi] = ol;
            so[gi] = fsig_(ol);
            mask[gi] = 0u;                   // fold memset in
        }

        if (r0a | r1a) {
            float so0 = fsig_(pred[off + 4]);
            float so1 = fsig_(pred[off + 85 + 4]);
            float x1 = pred[off + 64 + lane];          // pos 64..127
            if (r0a) {
                float x0 = pred[off + lane];           // pos 0..63
                float a0 = 0.0f;
                if (lane >= 5)  a0 += __logf(1.0f - fsqrt_(fsig_(x0) * so0) + 1e-7f);
                if (lane < 21)  a0 += __logf(1.0f - fsqrt_(fsig_(x1) * so0) + 1e-7f);
                #pragma unroll
                for (int o = 32; o; o >>= 1) a0 += __shfl_xor(a0, o);
                if (lane == 0) base[(size_t)b * NN + r0] = -a0;
            }
            if (r1a) {
                float x2 = (lane < 42) ? pred[off + 128 + lane] : 0.0f; // pos 128..169
                float a1 = 0.0f;
                if (lane >= 26) a1 += __logf(1.0f - fsqrt_(fsig_(x1) * so1) + 1e-7f);
                if (lane < 42)  a1 += __logf(1.0f - fsqrt_(fsig_(x2) * so1) + 1e-7f);
                #pragma unroll
                for (int o = 32; o; o >>= 1) a1 += __shfl_xor(a1, o);
                if (lane == 0) base[(size_t)b * NN + r0 + 1] = -a1;
            }
        }
    }
}

// ---- Kernel C: fused on-the-fly cost scan + dyn_k + assignment ------------
// Candidates are in-box only (proven output-equivalent: ti init 0.0 pads the
// top-10 sum with zeros bit-identically; selections are all in-box whenever
// any exist since dyn_k <= cnt_inbox; cnt==0 assigns nothing either way).
// Merge/extraction phases verbatim from the proven round-10 kC.
__global__ void __launch_bounds__(256) kC(const float* __restrict__ pred,
                                          const float* __restrict__ tgt,
                                          const float4* __restrict__ pxyxy,
                                          const float2* __restrict__ cxy,
                                          const float* __restrict__ base,
                                          const float* __restrict__ so,
                                          unsigned int* __restrict__ mask) {
    // remap so an image's 32 g-blocks share an XCD (L2 locality for gathers)
    const int x_ = blockIdx.x & 7, k_ = blockIdx.x >> 3;
    const int g = k_ & 31, b = ((k_ >> 5) << 3) | x_;
    const int tid = threadIdx.x;
    const int wid = tid >> 6, lane = tid & 63;

    const float* t = tgt + ((size_t)b * MM + g) * 5;
    const int gcls = (int)t[0];
    const float gx1 = t[1] - t[3] * 0.5f, gy1 = t[2] - t[4] * 0.5f;
    const float gx2 = t[1] + t[3] * 0.5f, gy2 = t[2] + t[4] * 0.5f;
    const float ga = fmaxf(gx2 - gx1, 0.0f) * fmaxf(gy2 - gy1, 0.0f);
    const size_t nb = (size_t)b * NN;

    float ti[TOPK];                 // top ious desc; init 0 == zero-padding
    float cv[TOPK]; int ci[TOPK];   // smallest (cost, n) lex
    #pragma unroll
    for (int j = 0; j < TOPK; ++j) { ti[j] = 0.0f; cv[j] = FLT_BIG; ci[j] = 0x7fffffff; }

    for (int n = tid; n < NN; n += 256) {    // per-thread n strictly increasing
        float2 c2 = cxy[nb + n];
        bool inb = (c2.x > gx1) && (c2.x < gx2) && (c2.y > gy1) && (c2.y < gy2);
        if (__ballot(inb) != 0ull) {         // wave-uniform: ~5% of waves active
            float4 pb = pxyxy[nb + n];
            float iou = iou_(pb, gx1, gy1, gx2, gy2, ga);
            float cl = pred[(nb + (size_t)n) * PD + 5 + gcls];
            float co = cost_(cl, so[nb + n], base[nb + n], iou);
            if (inb) {
                if (iou > ti[TOPK - 1]) {
                    ti[TOPK - 1] = iou;
                    #pragma unroll
                    for (int j = TOPK - 1; j > 0; --j)
                        if (ti[j] > ti[j - 1]) { float tm = ti[j-1]; ti[j-1] = ti[j]; ti[j] = tm; }
                }
                if (co < cv[TOPK - 1]) {     // strict <: equal cost keeps smaller n
                    cv[TOPK - 1] = co; ci[TOPK - 1] = n;
                    #pragma unroll
                    for (int j = TOPK - 1; j > 0; --j)
                        if (cv[j] < cv[j - 1]) {
                            float tv = cv[j-1]; cv[j-1] = cv[j]; cv[j] = tv;
                            int tn = ci[j-1]; ci[j-1] = ci[j]; ci[j] = tn;
                        }
                }
            }
        }
    }

    __shared__ float lv[256 * TOPK];
    __shared__ int   li[256 * TOPK];
    __shared__ float wv[4]; __shared__ int wn[4], wp[4];
    __shared__ float s_sum; __shared__ int s_dynk;

    // ---- Phase 1 merge: sum of global top-10 ious (descending add order) --
    #pragma unroll
    for (int j = 0; j < TOPK; ++j) lv[tid + 256 * j] = ti[j];
    __syncthreads();
    for (int p = 0; p < TOPK; ++p) {
        float bv = -2.0f; int bp = -1;
        #pragma unroll
        for (int j = 0; j < TOPK; ++j) {
            int idx = tid + 256 * j; float v = lv[idx];
            if (v > bv) { bv = v; bp = idx; }
        }
        for (int off = 32; off; off >>= 1) {
            float ov = __shfl_xor(bv, off); int op = __shfl_xor(bp, off);
            if (ov > bv || (ov == bv && op < bp)) { bv = ov; bp = op; }
        }
        if (lane == 0) { wv[wid] = bv; wp[wid] = bp; }
        __syncthreads();
        if (tid == 0) {
            float mb = wv[0]; int mp = wp[0];
            for (int w2 = 1; w2 < 4; ++w2)
                if (wv[w2] > mb || (wv[w2] == mb && wp[w2] < mp)) { mb = wv[w2]; mp = wp[w2]; }
            s_sum = (p == 0) ? mb : (s_sum + mb);
            lv[mp] = -2.0f;
        }
        __syncthreads();
    }
    if (tid == 0) {
        int k = (int)s_sum;          // trunc toward zero, sum >= 0
        if (k < 1) k = 1;
        if (k > TOPK) k = TOPK;
        s_dynk = k;
    }

    // ---- Phase 2 merge: dyn_k lexicographically-smallest (cost, n) --------
    #pragma unroll
    for (int j = 0; j < TOPK; ++j) { lv[tid + 256 * j] = cv[j]; li[tid + 256 * j] = ci[j]; }
    __syncthreads();
    const int dynk = s_dynk;
    for (int p = 0; p < dynk; ++p) {
        float bv = FLT_BIG; int bn = 0x7fffffff; int bp = -1;
        #pragma unroll
        for (int j = 0; j < TOPK; ++j) {
            int idx = tid + 256 * j; float v = lv[idx]; int nn2 = li[idx];
            if (v < bv || (v == bv && nn2 < bn)) { bv = v; bn = nn2; bp = idx; }
        }
        for (int off = 32; off; off >>= 1) {
            float ov = __shfl_xor(bv, off);
            int on = __shfl_xor(bn, off);
            int op = __shfl_xor(bp, off);
            if (ov < bv || (ov == bv && on < bn)) { bv = ov; bn = on; bp = op; }
        }
        if (lane == 0) { wv[wid] = bv; wn[wid] = bn; wp[wid] = bp; }
        __syncthreads();
        if (tid == 0) {
            float mb = wv[0]; int mn = wn[0], mp = wp[0];
            for (int w2 = 1; w2 < 4; ++w2)
                if (wv[w2] < mb || (wv[w2] == mb && wn[w2] < mn)) { mb = wv[w2]; mn = wn[w2]; mp = wp[w2]; }
            if (bp >= 0 || mp >= 0) { lv[mp] = FLT_BIG; li[mp] = 0x7fffffff; }
            if (mb < 5.0e4f)   // real candidate (in-box cost << 5e4; pads = FLT_BIG)
                atomicOr(&mask[(size_t)b * NN + mn], 1u << g);
        }
        __syncthreads();
    }
}

// ---- Kernel D: compacted fg, item-parallel class BCE; argmin recomputes ---
__global__ void __launch_bounds__(256) kD(const float* __restrict__ pred,
                   const float* __restrict__ tgt,
                   const float4* __restrict__ pxyxy,
                   const float* __restrict__ base,
                   const float* __restrict__ so,
                   const float* __restrict__ objlogit,
                   const unsigned int* __restrict__ mask,
                   float* __restrict__ partials) {
    const int tid = threadIdx.x;
    const int i0 = blockIdx.x * 256;
    const int i = i0 + tid;                 // BB*NN == 1050*256 exactly
    const int lane = tid & 63, wid = tid >> 6;
    const int b = i / NN;

    float obj_l, cls_l = 0.0f, reg_l = 0.0f, nfg = 0.0f;
    const unsigned int mk = mask[i];
    obj_l = bcef_(objlogit[i], mk ? 1.0f : 0.0f);

    __shared__ int s_list[256];
    __shared__ int s_gcls[256];
    __shared__ int s_wbase[4];
    __shared__ int s_cnt;

    unsigned long long bal = __ballot(mk != 0);
    int wpos = __popcll(bal & ((1ull << lane) - 1ull));
    if (lane == 0) s_wbase[wid] = __popcll(bal);
    __syncthreads();
    if (tid == 0) {
        int acc = 0;
        for (int w = 0; w < 4; ++w) { int t_ = s_wbase[w]; s_wbase[w] = acc; acc += t_; }
        s_cnt = acc;
    }
    __syncthreads();

    if (mk) {
        int e = s_wbase[wid] + wpos;
        s_list[e] = tid;
        nfg = 1.0f;
        float4 pb = pxyxy[i];
        float base_n = base[i], so_n = so[i];
        // matched gt: first-min over set bits; cost recomputed (assigned => in-box)
        float best = 3.0e30f; int bg = 0;
        for (int g = 0; g < MM; ++g) {
            if ((mk >> g) & 1u) {
                const float* tg = tgt + ((size_t)b * MM + g) * 5;
                float ggx1 = tg[1] - tg[3] * 0.5f, ggy1 = tg[2] - tg[4] * 0.5f;
                float ggx2 = tg[1] + tg[3] * 0.5f, ggy2 = tg[2] + tg[4] * 0.5f;
                float gga = fmaxf(ggx2 - ggx1, 0.0f) * fmaxf(ggy2 - ggy1, 0.0f);
                float iou = iou_(pb, ggx1, ggy1, ggx2, ggy2, gga);
                float cl = pred[(size_t)i * PD + 5 + (int)tg[0]];
                float cvv = cost_(cl, so_n, base_n, iou);
                if (cvv < best) { best = cvv; bg = g; }
            }
        }
        const float* tm = tgt + ((size_t)b * MM + bg) * 5;
        s_gcls[e] = (int)tm[0];
        // giou(pxyxy, matched gxyxy) — precise libm path feeds output
        float px1 = pb.x, py1 = pb.y, px2 = pb.z, py2 = pb.w;
        float tx1 = tm[1] - tm[3] * 0.5f, ty1 = tm[2] - tm[4] * 0.5f;
        float tx2 = tm[1] + tm[3] * 0.5f, ty2 = tm[2] + tm[4] * 0.5f;
        float ix1 = fmaxf(px1, tx1), iy1 = fmaxf(py1, ty1);
        float ix2 = fminf(px2, tx2), iy2 = fminf(py2, ty2);
        float inter = fmaxf(ix2 - ix1, 0.0f) * fmaxf(iy2 - iy1, 0.0f);
        float pa = fmaxf(px2 - px1, 0.0f) * fmaxf(py2 - py1, 0.0f);
        float ta = fmaxf(tx2 - tx1, 0.0f) * fmaxf(ty2 - ty1, 0.0f);
        float uni = pa + ta - inter + 1e-7f;
        float iou = inter / uni;
        float ex1 = fminf(px1, tx1), ey1 = fminf(py1, ty1);
        float ex2 = fmaxf(px2, tx2), ey2 = fmaxf(py2, ty2);
        float enclose = (ex2 - ex1) * (ey2 - ey1) + 1e-7f;
        float giou = iou - (enclose - uni) / enclose;
        reg_l = 1.0f - giou;
    }
    __syncthreads();

    const int cnt = s_cnt;
    const int nitems = cnt * NC;
    for (int item = tid; item < nitems; item += 256) {
        int e = item / NC;
        int c = item - e * NC;
        int gi = i0 + s_list[e];
        float x = pred[(size_t)gi * PD + 5 + c];
        cls_l += bcef_(x, (c == s_gcls[e]) ? 1.0f : 0.0f);
    }

    __shared__ float red[256];
    float sums[4] = {cls_l, obj_l, reg_l, nfg};
    float out4[4];
    for (int j = 0; j < 4; ++j) {
        red[tid] = sums[j];
        __syncthreads();
        for (int off = 128; off > 0; off >>= 1) {
            if (tid < off) red[tid] += red[tid + off];
            __syncthreads();
        }
        out4[j] = red[0];
        __syncthreads();
    }
    if (tid == 0) {
        float* pr = partials + (size_t)blockIdx.x * 4;
        pr[0] = out4[0]; pr[1] = out4[1]; pr[2] = out4[2]; pr[3] = out4[3];
    }
}

// ---- Kernel E: final deterministic reduction -----------------------------
__global__ void kE(const float* __restrict__ partials, int nblk, float* __restrict__ out) {
    __shared__ float red[256];
    float s[4] = {0, 0, 0, 0};
    for (int i = threadIdx.x; i < nblk; i += 256) {
        s[0] += partials[(size_t)i * 4 + 0];
        s[1] += partials[(size_t)i * 4 + 1];
        s[2] += partials[(size_t)i * 4 + 2];
        s[3] += partials[(size_t)i * 4 + 3];
    }
    float tot[4];
    for (int j = 0; j < 4; ++j) {
        red[threadIdx.x] = s[j];
        __syncthreads();
        for (int off = 128; off > 0; off >>= 1) {
            if (threadIdx.x < off) red[threadIdx.x] += red[threadIdx.x + off];
            __syncthreads();
        }
        tot[j] = red[0];
        __syncthreads();
    }
    if (threadIdx.x == 0) {
        float nfg = fmaxf(tot[3], 1.0f);
        out[0] = (tot[0] + tot[1] + 5.0f * tot[2]) / nfg;
    }
}

extern "C" void kernel_launch(void* const* d_in, const int* in_sizes, int n_in,
                              void* d_out, int out_size, void* d_ws, size_t ws_size,
                              hipStream_t stream) {
    const float* pred = (const float*)d_in[0];   // (B, N, 85) f32
    const float* tgt  = (const float*)d_in[1];   // (B, M, 5)  f32
    float* out = (float*)d_out;

    // Workspace layout (~12 MB; no cost matrix anymore)
    char* ws = (char*)d_ws;
    size_t off = 0;
    float4* pxyxy = (float4*)(ws + off);            off += (size_t)BB * NN * sizeof(float4);
    float2* cxy = (float2*)(ws + off);              off += (size_t)BB * NN * sizeof(float2);
    float* base = (float*)(ws + off);               off += (size_t)BB * NN * sizeof(float);
    float* so = (float*)(ws + off);                 off += (size_t)BB * NN * sizeof(float);
    float* objlogit = (float*)(ws + off);           off += (size_t)BB * NN * sizeof(float);
    unsigned int* mask = (unsigned int*)(ws + off); off += (size_t)BB * NN * sizeof(unsigned int);
    float* partials = (float*)(ws + off);

    const int nblk = (BB * NN + 255) / 256;  // 1050

    dim3 gA(NN / 16, BB);                    // 525 x 32; zeroes mask internally
    kA<<<gA, 256, 0, stream>>>(pred, tgt, pxyxy, cxy, base, so, objlogit, mask);

    kC<<<MM * BB, 256, 0, stream>>>(pred, tgt, pxyxy, cxy, base, so, mask);

    kD<<<nblk, 256, 0, stream>>>(pred, tgt, pxyxy, base, so, objlogit, mask, partials);

    kE<<<1, 256, 0, stream>>>(partials, nblk, out);
}

// Round 12
// 109.389 us; speedup vs baseline: 1.0529x; 1.0529x over previous
//
#include <hip/hip_runtime.h>
#include <math.h>

#define BB 32
#define NN 8400
#define MM 32
#define NC 80
#define PD 85
#define TOPK 10
#define FLT_BIG 3.4e38f

__device__ __forceinline__ float bcef_(float x, float t) {
    return fmaxf(x, 0.0f) - x * t + log1pf(expf(-fabsf(x)));
}

// fast hardware-native helpers: v_exp/v_log/v_rcp/v_sqrt, ~1-2 ulp
__device__ __forceinline__ float frcp_(float x)  { return __builtin_amdgcn_rcpf(x); }
__device__ __forceinline__ float fsqrt_(float x) { return __builtin_amdgcn_sqrtf(x); }
__device__ __forceinline__ float fsig_(float x)  { return frcp_(1.0f + __expf(-x)); }

// shared by kC and kD so matched-gt argmin sees bit-consistent costs
__device__ __forceinline__ float iou_(float4 pb, float gx1, float gy1,
                                      float gx2, float gy2, float ga) {
    float ix1 = fmaxf(gx1, pb.x), iy1 = fmaxf(gy1, pb.y);
    float ix2 = fminf(gx2, pb.z), iy2 = fminf(gy2, pb.w);
    float inter = fmaxf(ix2 - ix1, 0.0f) * fmaxf(iy2 - iy1, 0.0f);
    float pa = fmaxf(pb.z - pb.x, 0.0f) * fmaxf(pb.w - pb.y, 0.0f);
    float uni = ga + pa - inter + 1e-7f;
    return inter * frcp_(uni);
}
__device__ __forceinline__ float cost_(float cl, float so_n, float base_n, float iou) {
    float s = fsqrt_(fsig_(cl) * so_n);
    float lp = __logf(s + 1e-7f);
    float lq = __logf(1.0f - s + 1e-7f);
    return base_n - lp + lq - 3.0f * __logf(iou + 1e-8f);
}

// ---- Kernel A: per-row precompute — old-kAB load structure ----------------
// x0/x1 loaded UNCONDITIONALLY & coalesced first (no dependent header chain);
// headers via shfl from registers. Only the class-sum transcendentals and the
// x2 load are conditional on per-row in-box ballots.
__global__ void __launch_bounds__(256) kA(const float* __restrict__ pred,
                                          const float* __restrict__ tgt,
                                          float4* __restrict__ pxyxy,
                                          float2* __restrict__ cxy,
                                          float* __restrict__ base,
                                          float* __restrict__ so,
                                          float* __restrict__ objlogit,
                                          unsigned int* __restrict__ mask) {
    const int tid = threadIdx.x;
    const int lane = tid & 63, wid = tid >> 6;
    const int rs = lane >> 5, g = lane & 31;
    const int b = blockIdx.y;
    const int tile = blockIdx.x;             // 525 tiles of 16 rows

    // per-lane GT box (for in-box test)
    const float* t = tgt + ((size_t)b * MM + g) * 5;
    const float gx1 = t[1] - t[3] * 0.5f, gy1 = t[2] - t[4] * 0.5f;
    const float gx2 = t[1] + t[3] * 0.5f, gy2 = t[2] + t[4] * 0.5f;

    for (int itr = 0; itr < 2; ++itr) {
        const int pl = wid * 2 + itr;        // pair-local 0..7
        const int r0 = tile * 16 + pl * 2;   // global row (even)
        const size_t off = ((size_t)b * NN + r0) * PD;

        float x0 = pred[off + lane];                     // pos 0..63 (coalesced)
        float x1 = pred[off + 64 + lane];                // pos 64..127 (coalesced)

        // headers via shfl: row0 pos 0..4 (x0 lanes 0-4), row1 pos 85..89 (x1 lanes 21-25)
        float cx0 = __shfl(x0, 0), cy0 = __shfl(x0, 1), w0 = __shfl(x0, 2), h0 = __shfl(x0, 3), ol0 = __shfl(x0, 4);
        float cx1 = __shfl(x1, 21), cy1 = __shfl(x1, 22), w1 = __shfl(x1, 23), h1 = __shfl(x1, 24), ol1 = __shfl(x1, 25);
        float so0 = fsig_(ol0), so1 = fsig_(ol1);

        // per-row small outputs from registers
        const size_t gi = (size_t)b * NN + r0;
        if (lane == 0) {
            pxyxy[gi] = make_float4(cx0 - w0 * 0.5f, cy0 - h0 * 0.5f,
                                    cx0 + w0 * 0.5f, cy0 + h0 * 0.5f);
            cxy[gi] = make_float2(cx0, cy0);
            objlogit[gi] = ol0; so[gi] = so0;
        } else if (lane == 1) {
            pxyxy[gi + 1] = make_float4(cx1 - w1 * 0.5f, cy1 - h1 * 0.5f,
                                        cx1 + w1 * 0.5f, cy1 + h1 * 0.5f);
            cxy[gi + 1] = make_float2(cx1, cy1);
            objlogit[gi + 1] = ol1; so[gi + 1] = so1;
        } else if (lane == 2) mask[gi] = 0u;             // fold memset in
        else if (lane == 3) mask[gi + 1] = 0u;

        // in-box ballot per row (lanes 0-31: row0 x g; lanes 32-63: row1 x g)
        const float cxs = rs ? cx1 : cx0, cys = rs ? cy1 : cy0;
        const bool inb = (cxs > gx1) && (cxs < gx2) && (cys > gy1) && (cys < gy2);
        const unsigned long long bal = __ballot(inb);
        const bool r0a = (bal & 0xFFFFFFFFull) != 0ull;
        const bool r1a = (bal >> 32) != 0ull;

        if (r0a) {   // row0 class sum: pos 5..84 = x0(lane>=5) + x1(lane<21)
            float a0 = 0.0f;
            if (lane >= 5)  a0 += __logf(1.0f - fsqrt_(fsig_(x0) * so0) + 1e-7f);
            if (lane < 21)  a0 += __logf(1.0f - fsqrt_(fsig_(x1) * so0) + 1e-7f);
            #pragma unroll
            for (int o = 32; o; o >>= 1) a0 += __shfl_xor(a0, o);
            if (lane == 0) base[gi] = -a0;
        }
        if (r1a) {   // row1 class sum: pos 90..169 = x1(lane>=26) + x2(lane<42)
            float x2 = (lane < 42) ? pred[off + 128 + lane] : 0.0f;
            float a1 = 0.0f;
            if (lane >= 26) a1 += __logf(1.0f - fsqrt_(fsig_(x1) * so1) + 1e-7f);
            if (lane < 42)  a1 += __logf(1.0f - fsqrt_(fsig_(x2) * so1) + 1e-7f);
            #pragma unroll
            for (int o = 32; o; o >>= 1) a1 += __shfl_xor(a1, o);
            if (lane == 0) base[gi + 1] = -a1;
        }
    }
}

// ---- Kernel C: fused on-the-fly cost scan + dyn_k + assignment ------------
// (unchanged from round 11 — passing)
__global__ void __launch_bounds__(256) kC(const float* __restrict__ pred,
                                          const float* __restrict__ tgt,
                                          const float4* __restrict__ pxyxy,
                                          const float2* __restrict__ cxy,
                                          const float* __restrict__ base,
                                          const float* __restrict__ so,
                                          unsigned int* __restrict__ mask) {
    // remap so an image's 32 g-blocks share an XCD (L2 locality for gathers)
    const int x_ = blockIdx.x & 7, k_ = blockIdx.x >> 3;
    const int g = k_ & 31, b = ((k_ >> 5) << 3) | x_;
    const int tid = threadIdx.x;
    const int wid = tid >> 6, lane = tid & 63;

    const float* t = tgt + ((size_t)b * MM + g) * 5;
    const int gcls = (int)t[0];
    const float gx1 = t[1] - t[3] * 0.5f, gy1 = t[2] - t[4] * 0.5f;
    const float gx2 = t[1] + t[3] * 0.5f, gy2 = t[2] + t[4] * 0.5f;
    const float ga = fmaxf(gx2 - gx1, 0.0f) * fmaxf(gy2 - gy1, 0.0f);
    const size_t nb = (size_t)b * NN;

    float ti[TOPK];                 // top ious desc; init 0 == zero-padding
    float cv[TOPK]; int ci[TOPK];   // smallest (cost, n) lex
    #pragma unroll
    for (int j = 0; j < TOPK; ++j) { ti[j] = 0.0f; cv[j] = FLT_BIG; ci[j] = 0x7fffffff; }

    for (int n = tid; n < NN; n += 256) {    // per-thread n strictly increasing
        float2 c2 = cxy[nb + n];
        bool inb = (c2.x > gx1) && (c2.x < gx2) && (c2.y > gy1) && (c2.y < gy2);
        if (__ballot(inb) != 0ull) {         // wave-uniform: ~5% of waves active
            float4 pb = pxyxy[nb + n];
            float iou = iou_(pb, gx1, gy1, gx2, gy2, ga);
            float cl = pred[(nb + (size_t)n) * PD + 5 + gcls];
            float co = cost_(cl, so[nb + n], base[nb + n], iou);
            if (inb) {
                if (iou > ti[TOPK - 1]) {
                    ti[TOPK - 1] = iou;
                    #pragma unroll
                    for (int j = TOPK - 1; j > 0; --j)
                        if (ti[j] > ti[j - 1]) { float tm = ti[j-1]; ti[j-1] = ti[j]; ti[j] = tm; }
                }
                if (co < cv[TOPK - 1]) {     // strict <: equal cost keeps smaller n
                    cv[TOPK - 1] = co; ci[TOPK - 1] = n;
                    #pragma unroll
                    for (int j = TOPK - 1; j > 0; --j)
                        if (cv[j] < cv[j - 1]) {
                            float tv = cv[j-1]; cv[j-1] = cv[j]; cv[j] = tv;
                            int tn = ci[j-1]; ci[j-1] = ci[j]; ci[j] = tn;
                        }
                }
            }
        }
    }

    __shared__ float lv[256 * TOPK];
    __shared__ int   li[256 * TOPK];
    __shared__ float wv[4]; __shared__ int wn[4], wp[4];
    __shared__ float s_sum; __shared__ int s_dynk;

    // ---- Phase 1 merge: sum of global top-10 ious (descending add order) --
    #pragma unroll
    for (int j = 0; j < TOPK; ++j) lv[tid + 256 * j] = ti[j];
    __syncthreads();
    for (int p = 0; p < TOPK; ++p) {
        float bv = -2.0f; int bp = -1;
        #pragma unroll
        for (int j = 0; j < TOPK; ++j) {
            int idx = tid + 256 * j; float v = lv[idx];
            if (v > bv) { bv = v; bp = idx; }
        }
        for (int off = 32; off; off >>= 1) {
            float ov = __shfl_xor(bv, off); int op = __shfl_xor(bp, off);
            if (ov > bv || (ov == bv && op < bp)) { bv = ov; bp = op; }
        }
        if (lane == 0) { wv[wid] = bv; wp[wid] = bp; }
        __syncthreads();
        if (tid == 0) {
            float mb = wv[0]; int mp = wp[0];
            for (int w2 = 1; w2 < 4; ++w2)
                if (wv[w2] > mb || (wv[w2] == mb && wp[w2] < mp)) { mb = wv[w2]; mp = wp[w2]; }
            s_sum = (p == 0) ? mb : (s_sum + mb);
            lv[mp] = -2.0f;
        }
        __syncthreads();
    }
    if (tid == 0) {
        int k = (int)s_sum;          // trunc toward zero, sum >= 0
        if (k < 1) k = 1;
        if (k > TOPK) k = TOPK;
        s_dynk = k;
    }

    // ---- Phase 2 merge: dyn_k lexicographically-smallest (cost, n) --------
    #pragma unroll
    for (int j = 0; j < TOPK; ++j) { lv[tid + 256 * j] = cv[j]; li[tid + 256 * j] = ci[j]; }
    __syncthreads();
    const int dynk = s_dynk;
    for (int p = 0; p < dynk; ++p) {
        float bv = FLT_BIG; int bn = 0x7fffffff; int bp = -1;
        #pragma unroll
        for (int j = 0; j < TOPK; ++j) {
            int idx = tid + 256 * j; float v = lv[idx]; int nn2 = li[idx];
            if (v < bv || (v == bv && nn2 < bn)) { bv = v; bn = nn2; bp = idx; }
        }
        for (int off = 32; off; off >>= 1) {
            float ov = __shfl_xor(bv, off);
            int on = __shfl_xor(bn, off);
            int op = __shfl_xor(bp, off);
            if (ov < bv || (ov == bv && on < bn)) { bv = ov; bn = on; bp = op; }
        }
        if (lane == 0) { wv[wid] = bv; wn[wid] = bn; wp[wid] = bp; }
        __syncthreads();
        if (tid == 0) {
            float mb = wv[0]; int mn = wn[0], mp = wp[0];
            for (int w2 = 1; w2 < 4; ++w2)
                if (wv[w2] < mb || (wv[w2] == mb && wn[w2] < mn)) { mb = wv[w2]; mn = wn[w2]; mp = wp[w2]; }
            lv[mp] = FLT_BIG; li[mp] = 0x7fffffff;
            if (mb < 5.0e4f)   // real candidate (in-box cost << 5e4; pads = FLT_BIG)
                atomicOr(&mask[(size_t)b * NN + mn], 1u << g);
        }
        __syncthreads();
    }
}

// ---- Kernel D: compacted fg, item-parallel class BCE; argmin recomputes ---
// (unchanged from round 11 — passing)
__global__ void __launch_bounds__(256) kD(const float* __restrict__ pred,
                   const float* __restrict__ tgt,
                   const float4* __restrict__ pxyxy,
                   const float* __restrict__ base,
                   const float* __restrict__ so,
                   const float* __restrict__ objlogit,
                   const unsigned int* __restrict__ mask,
                   float* __restrict__ partials) {
    const int tid = threadIdx.x;
    const int i0 = blockIdx.x * 256;
    const int i = i0 + tid;                 // BB*NN == 1050*256 exactly
    const int lane = tid & 63, wid = tid >> 6;
    const int b = i / NN;

    float obj_l, cls_l = 0.0f, reg_l = 0.0f, nfg = 0.0f;
    const unsigned int mk = mask[i];
    obj_l = bcef_(objlogit[i], mk ? 1.0f : 0.0f);

    __shared__ int s_list[256];
    __shared__ int s_gcls[256];
    __shared__ int s_wbase[4];
    __shared__ int s_cnt;

    unsigned long long bal = __ballot(mk != 0);
    int wpos = __popcll(bal & ((1ull << lane) - 1ull));
    if (lane == 0) s_wbase[wid] = __popcll(bal);
    __syncthreads();
    if (tid == 0) {
        int acc = 0;
        for (int w = 0; w < 4; ++w) { int t_ = s_wbase[w]; s_wbase[w] = acc; acc += t_; }
        s_cnt = acc;
    }
    __syncthreads();

    if (mk) {
        int e = s_wbase[wid] + wpos;
        s_list[e] = tid;
        nfg = 1.0f;
        float4 pb = pxyxy[i];
        float base_n = base[i], so_n = so[i];
        // matched gt: first-min over set bits; cost recomputed (assigned => in-box)
        float best = 3.0e30f; int bg = 0;
        for (int g = 0; g < MM; ++g) {
            if ((mk >> g) & 1u) {
                const float* tg = tgt + ((size_t)b * MM + g) * 5;
                float ggx1 = tg[1] - tg[3] * 0.5f, ggy1 = tg[2] - tg[4] * 0.5f;
                float ggx2 = tg[1] + tg[3] * 0.5f, ggy2 = tg[2] + tg[4] * 0.5f;
                float gga = fmaxf(ggx2 - ggx1, 0.0f) * fmaxf(ggy2 - ggy1, 0.0f);
                float iou = iou_(pb, ggx1, ggy1, ggx2, ggy2, gga);
                float cl = pred[(size_t)i * PD + 5 + (int)tg[0]];
                float cvv = cost_(cl, so_n, base_n, iou);
                if (cvv < best) { best = cvv; bg = g; }
            }
        }
        const float* tm = tgt + ((size_t)b * MM + bg) * 5;
        s_gcls[e] = (int)tm[0];
        // giou(pxyxy, matched gxyxy) — precise libm path feeds output
        float px1 = pb.x, py1 = pb.y, px2 = pb.z, py2 = pb.w;
        float tx1 = tm[1] - tm[3] * 0.5f, ty1 = tm[2] - tm[4] * 0.5f;
        float tx2 = tm[1] + tm[3] * 0.5f, ty2 = tm[2] + tm[4] * 0.5f;
        float ix1 = fmaxf(px1, tx1), iy1 = fmaxf(py1, ty1);
        float ix2 = fminf(px2, tx2), iy2 = fminf(py2, ty2);
        float inter = fmaxf(ix2 - ix1, 0.0f) * fmaxf(iy2 - iy1, 0.0f);
        float pa = fmaxf(px2 - px1, 0.0f) * fmaxf(py2 - py1, 0.0f);
        float ta = fmaxf(tx2 - tx1, 0.0f) * fmaxf(ty2 - ty1, 0.0f);
        float uni = pa + ta - inter + 1e-7f;
        float iou = inter / uni;
        float ex1 = fminf(px1, tx1), ey1 = fminf(py1, ty1);
        float ex2 = fmaxf(px2, tx2), ey2 = fmaxf(py2, ty2);
        float enclose = (ex2 - ex1) * (ey2 - ey1) + 1e-7f;
        float giou = iou - (enclose - uni) / enclose;
        reg_l = 1.0f - giou;
    }
    __syncthreads();

    const int cnt = s_cnt;
    const int nitems = cnt * NC;
    for (int item = tid; item < nitems; item += 256) {
        int e = item / NC;
        int c = item - e * NC;
        int gi = i0 + s_list[e];
        float x = pred[(size_t)gi * PD + 5 + c];
        cls_l += bcef_(x, (c == s_gcls[e]) ? 1.0f : 0.0f);
    }

    __shared__ float red[256];
    float sums[4] = {cls_l, obj_l, reg_l, nfg};
    float out4[4];
    for (int j = 0; j < 4; ++j) {
        red[tid] = sums[j];
        __syncthreads();
        for (int off = 128; off > 0; off >>= 1) {
            if (tid < off) red[tid] += red[tid + off];
            __syncthreads();
        }
        out4[j] = red[0];
        __syncthreads();
    }
    if (tid == 0) {
        float* pr = partials + (size_t)blockIdx.x * 4;
        pr[0] = out4[0]; pr[1] = out4[1]; pr[2] = out4[2]; pr[3] = out4[3];
    }
}

// ---- Kernel E: final deterministic reduction -----------------------------
__global__ void kE(const float* __restrict__ partials, int nblk, float* __restrict__ out) {
    __shared__ float red[256];
    float s[4] = {0, 0, 0, 0};
    for (int i = threadIdx.x; i < nblk; i += 256) {
        s[0] += partials[(size_t)i * 4 + 0];
        s[1] += partials[(size_t)i * 4 + 1];
        s[2] += partials[(size_t)i * 4 + 2];
        s[3] += partials[(size_t)i * 4 + 3];
    }
    float tot[4];
    for (int j = 0; j < 4; ++j) {
        red[threadIdx.x] = s[j];
        __syncthreads();
        for (int off = 128; off > 0; off >>= 1) {
            if (threadIdx.x < off) red[threadIdx.x] += red[threadIdx.x + off];
            __syncthreads();
        }
        tot[j] = red[0];
        __syncthreads();
    }
    if (threadIdx.x == 0) {
        float nfg = fmaxf(tot[3], 1.0f);
        out[0] = (tot[0] + tot[1] + 5.0f * tot[2]) / nfg;
    }
}

extern "C" void kernel_launch(void* const* d_in, const int* in_sizes, int n_in,
                              void* d_out, int out_size, void* d_ws, size_t ws_size,
                              hipStream_t stream) {
    const float* pred = (const float*)d_in[0];   // (B, N, 85) f32
    const float* tgt  = (const float*)d_in[1];   // (B, M, 5)  f32
    float* out = (float*)d_out;

    // Workspace layout (~12 MB; no cost matrix)
    char* ws = (char*)d_ws;
    size_t off = 0;
    float4* pxyxy = (float4*)(ws + off);            off += (size_t)BB * NN * sizeof(float4);
    float2* cxy = (float2*)(ws + off);              off += (size_t)BB * NN * sizeof(float2);
    float* base = (float*)(ws + off);               off += (size_t)BB * NN * sizeof(float);
    float* so = (float*)(ws + off);                 off += (size_t)BB * NN * sizeof(float);
    float* objlogit = (float*)(ws + off);           off += (size_t)BB * NN * sizeof(float);
    unsigned int* mask = (unsigned int*)(ws + off); off += (size_t)BB * NN * sizeof(unsigned int);
    float* partials = (float*)(ws + off);

    const int nblk = (BB * NN + 255) / 256;  // 1050

    dim3 gA(NN / 16, BB);                    // 525 x 32; zeroes mask internally
    kA<<<gA, 256, 0, stream>>>(pred, tgt, pxyxy, cxy, base, so, objlogit, mask);

    kC<<<MM * BB, 256, 0, stream>>>(pred, tgt, pxyxy, cxy, base, so, mask);

    kD<<<nblk, 256, 0, stream>>>(pred, tgt, pxyxy, base, so, objlogit, mask, partials);

    kE<<<1, 256, 0, stream>>>(partials, nblk, out);
}

// Round 13
// 95.440 us; speedup vs baseline: 1.2068x; 1.1462x over previous
//
#include <hip/hip_runtime.h>
#include <math.h>

#define BB 32
#define NN 8400
#define MM 32
#define NC 80
#define PD 85
#define TOPK 10
#define CAP 2048            // per-(b,g) candidate capacity (mean ~250, >50 sigma)
#define FLT_BIG 3.4e38f

__device__ __forceinline__ float bcef_(float x, float t) {
    return fmaxf(x, 0.0f) - x * t + log1pf(expf(-fabsf(x)));
}

// fast hardware-native helpers: v_exp/v_log/v_rcp/v_sqrt, ~1-2 ulp
__device__ __forceinline__ float frcp_(float x)  { return __builtin_amdgcn_rcpf(x); }
__device__ __forceinline__ float fsqrt_(float x) { return __builtin_amdgcn_sqrtf(x); }
__device__ __forceinline__ float fsig_(float x)  { return frcp_(1.0f + __expf(-x)); }

// shared by kC and kD so matched-gt argmin sees bit-consistent costs
__device__ __forceinline__ float iou_(float4 pb, float gx1, float gy1,
                                      float gx2, float gy2, float ga) {
    float ix1 = fmaxf(gx1, pb.x), iy1 = fmaxf(gy1, pb.y);
    float ix2 = fminf(gx2, pb.z), iy2 = fminf(gy2, pb.w);
    float inter = fmaxf(ix2 - ix1, 0.0f) * fmaxf(iy2 - iy1, 0.0f);
    float pa = fmaxf(pb.z - pb.x, 0.0f) * fmaxf(pb.w - pb.y, 0.0f);
    float uni = ga + pa - inter + 1e-7f;
    return inter * frcp_(uni);
}
__device__ __forceinline__ float cost_(float cl, float so_n, float base_n, float iou) {
    float s = fsqrt_(fsig_(cl) * so_n);
    float lp = __logf(s + 1e-7f);
    float lq = __logf(1.0f - s + 1e-7f);
    return base_n - lp + lq - 3.0f * __logf(iou + 1e-8f);
}

// ---- Kernel A: per-row precompute + in-box bitmask ------------------------
// Round-12 proven structure; additionally stores inmask[b][n] (bit g = center
// of pred n inside GT g) straight from the ballot it already computes.
__global__ void __launch_bounds__(256) kA(const float* __restrict__ pred,
                                          const float* __restrict__ tgt,
                                          float4* __restrict__ pxyxy,
                                          float* __restrict__ base,
                                          float* __restrict__ so,
                                          float* __restrict__ objlogit,
                                          unsigned int* __restrict__ inmask,
                                          unsigned int* __restrict__ mask) {
    const int tid = threadIdx.x;
    const int lane = tid & 63, wid = tid >> 6;
    const int rs = lane >> 5, g = lane & 31;
    const int b = blockIdx.y;
    const int tile = blockIdx.x;             // 525 tiles of 16 rows

    const float* t = tgt + ((size_t)b * MM + g) * 5;
    const float gx1 = t[1] - t[3] * 0.5f, gy1 = t[2] - t[4] * 0.5f;
    const float gx2 = t[1] + t[3] * 0.5f, gy2 = t[2] + t[4] * 0.5f;

    for (int itr = 0; itr < 2; ++itr) {
        const int pl = wid * 2 + itr;        // pair-local 0..7
        const int r0 = tile * 16 + pl * 2;   // global row (even)
        const size_t off = ((size_t)b * NN + r0) * PD;

        float x0 = pred[off + lane];                     // pos 0..63 (coalesced)
        float x1 = pred[off + 64 + lane];                // pos 64..127 (coalesced)

        float cx0 = __shfl(x0, 0), cy0 = __shfl(x0, 1), w0 = __shfl(x0, 2), h0 = __shfl(x0, 3), ol0 = __shfl(x0, 4);
        float cx1 = __shfl(x1, 21), cy1 = __shfl(x1, 22), w1 = __shfl(x1, 23), h1 = __shfl(x1, 24), ol1 = __shfl(x1, 25);
        float so0 = fsig_(ol0), so1 = fsig_(ol1);

        // in-box ballot (lanes 0-31: row0 x g; lanes 32-63: row1 x g)
        const float cxs = rs ? cx1 : cx0, cys = rs ? cy1 : cy0;
        const bool inb = (cxs > gx1) && (cxs < gx2) && (cys > gy1) && (cys < gy2);
        const unsigned long long bal = __ballot(inb);
        const bool r0a = (bal & 0xFFFFFFFFull) != 0ull;
        const bool r1a = (bal >> 32) != 0ull;

        // per-row small outputs from registers
        const size_t gi = (size_t)b * NN + r0;
        if (lane == 0) {
            pxyxy[gi] = make_float4(cx0 - w0 * 0.5f, cy0 - h0 * 0.5f,
                                    cx0 + w0 * 0.5f, cy0 + h0 * 0.5f);
            objlogit[gi] = ol0; so[gi] = so0;
        } else if (lane == 1) {
            pxyxy[gi + 1] = make_float4(cx1 - w1 * 0.5f, cy1 - h1 * 0.5f,
                                        cx1 + w1 * 0.5f, cy1 + h1 * 0.5f);
            objlogit[gi + 1] = ol1; so[gi + 1] = so1;
        } else if (lane == 2) mask[gi] = 0u;             // fold memset in
        else if (lane == 3) mask[gi + 1] = 0u;
        else if (lane == 4) inmask[gi] = (unsigned int)(bal & 0xFFFFFFFFull);
        else if (lane == 5) inmask[gi + 1] = (unsigned int)(bal >> 32);

        if (r0a) {   // row0 class sum: pos 5..84 = x0(lane>=5) + x1(lane<21)
            float a0 = 0.0f;
            if (lane >= 5)  a0 += __logf(1.0f - fsqrt_(fsig_(x0) * so0) + 1e-7f);
            if (lane < 21)  a0 += __logf(1.0f - fsqrt_(fsig_(x1) * so0) + 1e-7f);
            #pragma unroll
            for (int o = 32; o; o >>= 1) a0 += __shfl_xor(a0, o);
            if (lane == 0) base[gi] = -a0;
        }
        if (r1a) {   // row1 class sum: pos 90..169 = x1(lane>=26) + x2(lane<42)
            float x2 = (lane < 42) ? pred[off + 128 + lane] : 0.0f;
            float a1 = 0.0f;
            if (lane >= 26) a1 += __logf(1.0f - fsqrt_(fsig_(x1) * so1) + 1e-7f);
            if (lane < 42)  a1 += __logf(1.0f - fsqrt_(fsig_(x2) * so1) + 1e-7f);
            #pragma unroll
            for (int o = 32; o; o >>= 1) a1 += __shfl_xor(a1, o);
            if (lane == 0) base[gi + 1] = -a1;
        }
    }
}

// ---- Kernel C: bitmask scan -> candidate compaction -> 1-wave selection ---
// Candidates = in-box pairs only (proven output-equivalent). Compaction order
// is nondeterministic (LDS ticket) but selection is by (iou) / lex (cost, n)
// multiset -> output deterministic. cnt<10 pads the iou sum with zeros
// (bit-identical); p>=cnt assigns nothing (matches FLT_BIG-pad semantics).
__global__ void __launch_bounds__(256) kC(const float* __restrict__ pred,
                                          const float* __restrict__ tgt,
                                          const float4* __restrict__ pxyxy,
                                          const float* __restrict__ base,
                                          const float* __restrict__ so,
                                          const unsigned int* __restrict__ inmask,
                                          unsigned int* __restrict__ mask) {
    // remap so an image's 32 g-blocks share an XCD (L2 locality for gathers)
    const int x_ = blockIdx.x & 7, k_ = blockIdx.x >> 3;
    const int g = k_ & 31, b = ((k_ >> 5) << 3) | x_;
    const int tid = threadIdx.x;
    const int wid = tid >> 6, lane = tid & 63;

    const float* t = tgt + ((size_t)b * MM + g) * 5;
    const int gcls = (int)t[0];
    const float gx1 = t[1] - t[3] * 0.5f, gy1 = t[2] - t[4] * 0.5f;
    const float gx2 = t[1] + t[3] * 0.5f, gy2 = t[2] + t[4] * 0.5f;
    const float ga = fmaxf(gx2 - gx1, 0.0f) * fmaxf(gy2 - gy1, 0.0f);
    const size_t nb = (size_t)b * NN;
    const unsigned int gbit = 1u << g;

    __shared__ float s_iou[CAP];
    __shared__ float s_cost[CAP];
    __shared__ int   s_n[CAP];
    __shared__ int   s_cnt;
    if (tid == 0) s_cnt = 0;
    __syncthreads();

    for (int n = tid; n < NN; n += 256) {
        if (inmask[nb + n] & gbit) {         // compiler emits execz-skip per wave
            float4 pb = pxyxy[nb + n];
            float iou = iou_(pb, gx1, gy1, gx2, gy2, ga);
            float cl = pred[(nb + (size_t)n) * PD + 5 + gcls];
            float co = cost_(cl, so[nb + n], base[nb + n], iou);
            int idx = atomicAdd(&s_cnt, 1);
            if (idx < CAP) { s_iou[idx] = iou; s_cost[idx] = co; s_n[idx] = n; }
        }
    }
    __syncthreads();

    if (wid != 0) return;                    // wave 0 finishes alone (no barriers)
    const int cnt = min(s_cnt, CAP);

    // Phase 1: sum of top-10 ious, descending add order (register consumed-mask)
    float ssum = 0.0f;
    {
        unsigned int consumed = 0u;          // bit k = entry lane + 64*k (k<32)
        const int lim = (cnt < TOPK) ? cnt : TOPK;
        for (int p = 0; p < lim; ++p) {
            float bv = -1.0f; int bidx = 0x7fffffff;
            int k = 0;
            for (int i = lane; i < cnt; i += 64, ++k) {
                if (!((consumed >> k) & 1u)) {
                    float v = s_iou[i];
                    if (v > bv) { bv = v; bidx = i; }
                }
            }
            #pragma unroll
            for (int o = 32; o; o >>= 1) {
                float ov = __shfl_xor(bv, o); int oi = __shfl_xor(bidx, o);
                if (ov > bv || (ov == bv && oi < bidx)) { bv = ov; bidx = oi; }
            }
            ssum += bv;                      // uniform after reduce
            if ((bidx & 63) == lane) consumed |= 1u << (bidx >> 6);
        }
    }
    int dynk = (int)ssum;                    // trunc toward zero, sum in [0,10)
    if (dynk < 1) dynk = 1;
    if (dynk > TOPK) dynk = TOPK;

    // Phase 2: dyn_k lexicographically-smallest (cost, n) -> assignment bits
    {
        unsigned int consumed = 0u;
        const int lim = (cnt < dynk) ? cnt : dynk;
        for (int p = 0; p < lim; ++p) {
            float bv = FLT_BIG; int bn_ = 0x7fffffff; int bidx = -1;
            int k = 0;
            for (int i = lane; i < cnt; i += 64, ++k) {
                if (!((consumed >> k) & 1u)) {
                    float v = s_cost[i]; int n_ = s_n[i];
                    if (v < bv || (v == bv && n_ < bn_)) { bv = v; bn_ = n_; bidx = i; }
                }
            }
            #pragma unroll
            for (int o = 32; o; o >>= 1) {
                float ov = __shfl_xor(bv, o);
                int on = __shfl_xor(bn_, o);
                int oi = __shfl_xor(bidx, o);
                if (ov < bv || (ov == bv && on < bn_)) { bv = ov; bn_ = on; bidx = oi; }
            }
            if ((bidx & 63) == lane) consumed |= 1u << (bidx >> 6);
            if (lane == 0) atomicOr(&mask[nb + bn_], gbit);
        }
    }
}

// ---- Kernel D: compacted fg, item-parallel class BCE; argmin recomputes ---
// (unchanged from round 12 — passing)
__global__ void __launch_bounds__(256) kD(const float* __restrict__ pred,
                   const float* __restrict__ tgt,
                   const float4* __restrict__ pxyxy,
                   const float* __restrict__ base,
                   const float* __restrict__ so,
                   const float* __restrict__ objlogit,
                   const unsigned int* __restrict__ mask,
                   float* __restrict__ partials) {
    const int tid = threadIdx.x;
    const int i0 = blockIdx.x * 256;
    const int i = i0 + tid;                 // BB*NN == 1050*256 exactly
    const int lane = tid & 63, wid = tid >> 6;
    const int b = i / NN;

    float obj_l, cls_l = 0.0f, reg_l = 0.0f, nfg = 0.0f;
    const unsigned int mk = mask[i];
    obj_l = bcef_(objlogit[i], mk ? 1.0f : 0.0f);

    __shared__ int s_list[256];
    __shared__ int s_gcls[256];
    __shared__ int s_wbase[4];
    __shared__ int s_cnt;

    unsigned long long bal = __ballot(mk != 0);
    int wpos = __popcll(bal & ((1ull << lane) - 1ull));
    if (lane == 0) s_wbase[wid] = __popcll(bal);
    __syncthreads();
    if (tid == 0) {
        int acc = 0;
        for (int w = 0; w < 4; ++w) { int t_ = s_wbase[w]; s_wbase[w] = acc; acc += t_; }
        s_cnt = acc;
    }
    __syncthreads();

    if (mk) {
        int e = s_wbase[wid] + wpos;
        s_list[e] = tid;
        nfg = 1.0f;
        float4 pb = pxyxy[i];
        float base_n = base[i], so_n = so[i];
        float best = 3.0e30f; int bg = 0;
        for (int g = 0; g < MM; ++g) {
            if ((mk >> g) & 1u) {
                const float* tg = tgt + ((size_t)b * MM + g) * 5;
                float ggx1 = tg[1] - tg[3] * 0.5f, ggy1 = tg[2] - tg[4] * 0.5f;
                float ggx2 = tg[1] + tg[3] * 0.5f, ggy2 = tg[2] + tg[4] * 0.5f;
                float gga = fmaxf(ggx2 - ggx1, 0.0f) * fmaxf(ggy2 - ggy1, 0.0f);
                float iou = iou_(pb, ggx1, ggy1, ggx2, ggy2, gga);
                float cl = pred[(size_t)i * PD + 5 + (int)tg[0]];
                float cvv = cost_(cl, so_n, base_n, iou);
                if (cvv < best) { best = cvv; bg = g; }
            }
        }
        const float* tm = tgt + ((size_t)b * MM + bg) * 5;
        s_gcls[e] = (int)tm[0];
        float px1 = pb.x, py1 = pb.y, px2 = pb.z, py2 = pb.w;
        float tx1 = tm[1] - tm[3] * 0.5f, ty1 = tm[2] - tm[4] * 0.5f;
        float tx2 = tm[1] + tm[3] * 0.5f, ty2 = tm[2] + tm[4] * 0.5f;
        float ix1 = fmaxf(px1, tx1), iy1 = fmaxf(py1, ty1);
        float ix2 = fminf(px2, tx2), iy2 = fminf(py2, ty2);
        float inter = fmaxf(ix2 - ix1, 0.0f) * fmaxf(iy2 - iy1, 0.0f);
        float pa = fmaxf(px2 - px1, 0.0f) * fmaxf(py2 - py1, 0.0f);
        float ta = fmaxf(tx2 - tx1, 0.0f) * fmaxf(ty2 - ty1, 0.0f);
        float uni = pa + ta - inter + 1e-7f;
        float iou = inter / uni;
        float ex1 = fminf(px1, tx1), ey1 = fminf(py1, ty1);
        float ex2 = fmaxf(px2, tx2), ey2 = fmaxf(py2, ty2);
        float enclose = (ex2 - ex1) * (ey2 - ey1) + 1e-7f;
        float giou = iou - (enclose - uni) / enclose;
        reg_l = 1.0f - giou;
    }
    __syncthreads();

    const int cnt = s_cnt;
    const int nitems = cnt * NC;
    for (int item = tid; item < nitems; item += 256) {
        int e = item / NC;
        int c = item - e * NC;
        int gi = i0 + s_list[e];
        float x = pred[(size_t)gi * PD + 5 + c];
        cls_l += bcef_(x, (c == s_gcls[e]) ? 1.0f : 0.0f);
    }

    __shared__ float red[256];
    float sums[4] = {cls_l, obj_l, reg_l, nfg};
    float out4[4];
    for (int j = 0; j < 4; ++j) {
        red[tid] = sums[j];
        __syncthreads();
        for (int off = 128; off > 0; off >>= 1) {
            if (tid < off) red[tid] += red[tid + off];
            __syncthreads();
        }
        out4[j] = red[0];
        __syncthreads();
    }
    if (tid == 0) {
        float* pr = partials + (size_t)blockIdx.x * 4;
        pr[0] = out4[0]; pr[1] = out4[1]; pr[2] = out4[2]; pr[3] = out4[3];
    }
}

// ---- Kernel E: final deterministic reduction -----------------------------
__global__ void kE(const float* __restrict__ partials, int nblk, float* __restrict__ out) {
    __shared__ float red[256];
    float s[4] = {0, 0, 0, 0};
    for (int i = threadIdx.x; i < nblk; i += 256) {
        s[0] += partials[(size_t)i * 4 + 0];
        s[1] += partials[(size_t)i * 4 + 1];
        s[2] += partials[(size_t)i * 4 + 2];
        s[3] += partials[(size_t)i * 4 + 3];
    }
    float tot[4];
    for (int j = 0; j < 4; ++j) {
        red[threadIdx.x] = s[j];
        __syncthreads();
        for (int off = 128; off > 0; off >>= 1) {
            if (threadIdx.x < off) red[threadIdx.x] += red[threadIdx.x + off];
            __syncthreads();
        }
        tot[j] = red[0];
        __syncthreads();
    }
    if (threadIdx.x == 0) {
        float nfg = fmaxf(tot[3], 1.0f);
        out[0] = (tot[0] + tot[1] + 5.0f * tot[2]) / nfg;
    }
}

extern "C" void kernel_launch(void* const* d_in, const int* in_sizes, int n_in,
                              void* d_out, int out_size, void* d_ws, size_t ws_size,
                              hipStream_t stream) {
    const float* pred = (const float*)d_in[0];   // (B, N, 85) f32
    const float* tgt  = (const float*)d_in[1];   // (B, M, 5)  f32
    float* out = (float*)d_out;

    // Workspace layout (~11 MB)
    char* ws = (char*)d_ws;
    size_t off = 0;
    float4* pxyxy = (float4*)(ws + off);            off += (size_t)BB * NN * sizeof(float4);
    float* base = (float*)(ws + off);               off += (size_t)BB * NN * sizeof(float);
    float* so = (float*)(ws + off);                 off += (size_t)BB * NN * sizeof(float);
    float* objlogit = (float*)(ws + off);           off += (size_t)BB * NN * sizeof(float);
    unsigned int* inmask = (unsigned int*)(ws + off); off += (size_t)BB * NN * sizeof(unsigned int);
    unsigned int* mask = (unsigned int*)(ws + off); off += (size_t)BB * NN * sizeof(unsigned int);
    float* partials = (float*)(ws + off);

    const int nblk = (BB * NN + 255) / 256;  // 1050

    dim3 gA(NN / 16, BB);                    // 525 x 32; zeroes mask internally
    kA<<<gA, 256, 0, stream>>>(pred, tgt, pxyxy, base, so, objlogit, inmask, mask);

    kC<<<MM * BB, 256, 0, stream>>>(pred, tgt, pxyxy, base, so, inmask, mask);

    kD<<<nblk, 256, 0, stream>>>(pred, tgt, pxyxy, base, so, objlogit, mask, partials);

    kE<<<1, 256, 0, stream>>>(partials, nblk, out);
}